// Round 1
// 66.552 us; speedup vs baseline: 1.0417x; 1.0417x over previous
//
#include <hip/hip_runtime.h>
#include <math.h>

#ifndef M_PI
#define M_PI 3.14159265358979323846
#endif

// N=2048. Sum over unordered pairs i>j only (the per-pair term is symmetric
// under i<->j: d flips sign, uid <-> -ujd, so qq/qu/uu are all invariant).
// Reference's tril qq/qu sums count each unordered pair once; the uu term's
// explicit 0.5 x full-matrix also equals once-per-unordered-pair. So:
//   pot = (NORM/2pi) * sum_{i>j} t_ij
//
// Grid is COMPACT: only the 1056 (of 32x64=2048) tiles that intersect the
// strict lower triangle are launched. Linear tile id t maps to
//   bi = largest b with b(b+1) <= t   (row-chunk has 2*bi+2 j-tiles)
//   bj = t - bi(bi+1)
constexpr int N_ATOMS = 2048;
constexpr int BLOCK   = 64;               // one wave per block
constexpr int ICH     = 64;               // i-chunk per block
constexpr int JT      = 32;               // j-tile per block
constexpr int GI      = N_ATOMS / ICH;    // 32
constexpr int NPART   = GI * GI + GI;     // 32*33 = 1056 working tiles

__global__ __launch_bounds__(BLOCK) void ewald_pairs(
    const float* __restrict__ q, const float* __restrict__ r,
    const float* __restrict__ u, float* __restrict__ partial)
{
    const int t = blockIdx.x;

    // closed-form inverse of cum(bi) = bi*(bi+1), with integer fixup
    int bi = (int)((sqrtf((float)(4 * t + 1)) - 1.0f) * 0.5f);
    while ((bi + 1) * (bi + 2) <= t) ++bi;
    while (bi * (bi + 1) > t) --bi;
    const int bj = t - bi * (bi + 1);     // 0 .. 2*bi+1, always has j<i work

    const int i  = bi * ICH + threadIdx.x;
    const int j0 = bj * JT;

    const float qi  = q[i];
    const float rix = r[3 * i + 0], riy = r[3 * i + 1], riz = r[3 * i + 2];
    const float uix = u[3 * i + 0], uiy = u[3 * i + 1], uiz = u[3 * i + 2];

    const float C  = 0.79788456080286536f;  // 2a/sqrt(pi), a=1/sqrt(2); 2a^2*C == C
    const float PA = 0.23166036f;           // p * a, p = 0.3275911 (A&S 7.1.26)
    const float A1 = 0.254829592f, A2 = -0.284496736f, A3 = 1.421413741f;
    const float A4 = -1.453152027f, A5 = 1.061405429f;

    float acc = 0.0f;

#pragma unroll 8
    for (int jj = 0; jj < JT; ++jj) {
        const int j = j0 + jj;              // wave-uniform -> scalar loads
        const float qj  = q[j];
        const float rjx = r[3 * j + 0], rjy = r[3 * j + 1], rjz = r[3 * j + 2];
        const float ujx = u[3 * j + 0], ujy = u[3 * j + 1], ujz = u[3 * j + 2];

        const float dx = rjx - rix, dy = rjy - riy, dz = rjz - riz;  // r_j - r_i
        const float rsq = dx * dx + dy * dy + dz * dz;

        const float rinv = __builtin_amdgcn_rsqf(rsq);   // NaN path on diag is masked below
        const float rn   = rsq * rinv;
        const float g    = __expf(-0.5f * rsq);          // exp(-(a*rn)^2)

        // A&S 7.1.26: erf(x) = 1 - (a1 t + ... + a5 t^5) e^{-x^2}, t = 1/(1+p*x)
        const float t5 = __builtin_amdgcn_rcpf(fmaf(PA, rn, 1.0f));
        const float poly = t5 * fmaf(t5, fmaf(t5, fmaf(t5, fmaf(t5, A5, A4), A3), A2), A1);
        const float erfv = 1.0f - poly * g;

        const float rinv2 = rinv * rinv;
        const float er3   = erfv * rinv2 * rinv;
        const float Cg    = C * g;
        const float cg2   = Cg * rinv2;
        const float s1    = er3 - cg2;                         // erf/r^3 - c g/r^2
        const float s2    = fmaf(3.0f, er3, -2.0f * cg2) - Cg; // + uses 2a^2 c == c

        const float uid  = uix * dx + uiy * dy + uiz * dz;
        const float ujd  = ujx * dx + ujy * dy + ujz * dz;
        const float uiuj = uix * ujx + uiy * ujy + uiz * ujz;

        const float tt = qi * qj * erfv * rinv
                       - s1 * (uid * qj - qi * ujd)
                       - (s2 * rinv2 * uid * ujd - s1 * uiuj);

        acc += (j < i) ? tt : 0.0f;         // excludes diagonal & upper triangle
    }

    for (int off = 32; off > 0; off >>= 1)
        acc += __shfl_down(acc, off, 64);
    if (threadIdx.x == 0) partial[t] = acc;
}

__global__ __launch_bounds__(256) void ewald_reduce(
    const float* __restrict__ partial, float* __restrict__ out)
{
    __shared__ float swave[4];
    float v = 0.0f;
    for (int k = threadIdx.x; k < NPART; k += 256) v += partial[k];
    for (int off = 32; off > 0; off >>= 1)
        v += __shfl_down(v, off, 64);
    if ((threadIdx.x & 63) == 0) swave[threadIdx.x >> 6] = v;
    __syncthreads();
    if (threadIdx.x == 0) {
        const float SCALE = (float)(90.0474 / (2.0 * M_PI));  // pairs counted once
        out[0] = (swave[0] + swave[1] + swave[2] + swave[3]) * SCALE;
    }
}

extern "C" void kernel_launch(void* const* d_in, const int* in_sizes, int n_in,
                              void* d_out, int out_size, void* d_ws, size_t ws_size,
                              hipStream_t stream) {
    const float* q = (const float*)d_in[0];   // (2048,)
    const float* r = (const float*)d_in[1];   // (2048,3)
    const float* u = (const float*)d_in[2];   // (2048,3)
    float* partial = (float*)d_ws;            // NPART floats

    ewald_pairs<<<dim3(NPART), BLOCK, 0, stream>>>(q, r, u, partial);
    ewald_reduce<<<1, 256, 0, stream>>>(partial, (float*)d_out);
}